// Round 8
// baseline (201.321 us; speedup 1.0000x reference)
//
#include <hip/hip_runtime.h>
#include <hip/hip_bf16.h>

// InfoNCE loss, B=4096 D=768 N=8192, T=0.5, fp32 in, fp32 scalar out.
// R8: MX-fp8 32x32x64, 128x128 tile, 256 threads / 4 waves, each wave a 64x64
// QUADRANT (2x2 MFMA): 2 KB LDS read per MFMA vs R7's 4 KB (B-frag never
// reused in 32x128 strips) -> LDS read traffic 1.6 GB -> 0.8 GB.
// acc = 4x f32x16 (~64 regs, AGPR-backed); NO launch_bounds reg cap (R5/R6
// lesson: caps make the compiler spill MFMA accumulators to scratch).
// XOR chunk swizzle kept (R6: conflicts 1.2e7 -> 4.0e6).

#define B_SZ 4096
#define D_SZ 768
#define N_SZ 8192
constexpr float INV_T = 2.0f;  // 1/temperature

typedef float f32x16 __attribute__((ext_vector_type(16)));
typedef int i32x8 __attribute__((ext_vector_type(8)));
typedef int i32x4 __attribute__((ext_vector_type(4)));
typedef __attribute__((address_space(1))) const unsigned int gu32;
typedef __attribute__((address_space(3))) unsigned int lu32;

__device__ inline void async16(const void* g, void* l) {
    // per-lane global addr, wave-uniform LDS base; lane i lands at base + i*16.
    __builtin_amdgcn_global_load_lds((gu32*)g, (lu32*)l, 16, 0, 0);
}

// ---- 1) fused prep: norms + positives + e4m3 rows + rowsum zeroing ----
__global__ __launch_bounds__(256) void prep_k(const float* __restrict__ h1,
                                              const float* __restrict__ h2,
                                              unsigned char* __restrict__ hn8,
                                              float* __restrict__ pos,
                                              float* __restrict__ rowsum) {
    const int i = blockIdx.x * 4 + (threadIdx.x >> 6);
    const int lane = threadIdx.x & 63;
    const float4* a4 = (const float4*)(h1 + (size_t)i * D_SZ);
    const float4* b4 = (const float4*)(h2 + (size_t)i * D_SZ);
    float4 av[3], bv[3];
    float sa = 0.f, sb = 0.f, dt = 0.f;
#pragma unroll
    for (int j = 0; j < 3; ++j) {
        av[j] = a4[lane + j * 64];
        bv[j] = b4[lane + j * 64];
        sa += av[j].x * av[j].x + av[j].y * av[j].y + av[j].z * av[j].z + av[j].w * av[j].w;
        sb += bv[j].x * bv[j].x + bv[j].y * bv[j].y + bv[j].z * bv[j].z + bv[j].w * bv[j].w;
        dt += av[j].x * bv[j].x + av[j].y * bv[j].y + av[j].z * bv[j].z + av[j].w * bv[j].w;
    }
#pragma unroll
    for (int m = 1; m < 64; m <<= 1) {
        sa += __shfl_xor(sa, m, 64);
        sb += __shfl_xor(sb, m, 64);
        dt += __shfl_xor(dt, m, 64);
    }
    const float n1 = fmaxf(sqrtf(sa), 1e-8f), n2 = fmaxf(sqrtf(sb), 1e-8f);
    const float i1 = 1.0f / n1, i2 = 1.0f / n2;
    unsigned int* d1 = (unsigned int*)(hn8 + (size_t)i * D_SZ);
    unsigned int* d2 = (unsigned int*)(hn8 + (size_t)(i + B_SZ) * D_SZ);
#pragma unroll
    for (int j = 0; j < 3; ++j) {
        unsigned int u1 = __builtin_amdgcn_cvt_pk_fp8_f32(av[j].x * i1, av[j].y * i1, 0, false);
        u1 = __builtin_amdgcn_cvt_pk_fp8_f32(av[j].z * i1, av[j].w * i1, u1, true);
        unsigned int u2 = __builtin_amdgcn_cvt_pk_fp8_f32(bv[j].x * i2, bv[j].y * i2, 0, false);
        u2 = __builtin_amdgcn_cvt_pk_fp8_f32(bv[j].z * i2, bv[j].w * i2, u2, true);
        d1[lane + j * 64] = u1;
        d2[lane + j * 64] = u2;
    }
    if (lane == 0) {
        float p = dt * i1 * i2 * INV_T;
        pos[i] = p;
        pos[i + B_SZ] = p;
        rowsum[i] = 0.f;  // ws re-poisoned each call; zero here
        rowsum[i + B_SZ] = 0.f;
    }
}

// ---- 2) symmetric fused sim-GEMM (MX-fp8, 32x32x64) + exp-rowsum ----
// 128x128 tile, 4 waves; wave w = quadrant (wq_m=w>>1, wq_n=w&1), 64x64 each.
// Unpadded 64 B LDS rows for global_load_lds w16; chunk-XOR swizzle for banks.
#define BM 128
#define BN 128
#define BKB 64  // fp8 bytes along K per iter

__global__ __launch_bounds__(256) void gemm_reduce_k(const unsigned char* __restrict__ hn8,
                                                     float* __restrict__ rowsum) {
    __shared__ __align__(16) unsigned char As[BM * BKB];  // 8 KB
    __shared__ __align__(16) unsigned char Bs[BN * BKB];  // 8 KB
    // triangular index -> (ty, tx), ty <= tx
    const int b = blockIdx.x;
    int tx = (int)((sqrtf(8.0f * (float)b + 1.0f) - 1.0f) * 0.5f);
    while ((tx + 1) * (tx + 2) / 2 <= b) ++tx;
    while (tx * (tx + 1) / 2 > b) --tx;
    const int ty = b - tx * (tx + 1) / 2;
    const int rowBase = ty * BM;
    const int colBase = tx * BN;
    const bool diagBlk = (ty == tx);

    const int tid = threadIdx.x;
    const int wave = tid >> 6;   // 0..3
    const int lane = tid & 63;
    const int l32 = lane & 31;
    const int half = lane >> 5;
    const int wq_m = wave >> 1;  // m-half (64 rows)
    const int wq_n = wave & 1;   // n-half (64 cols)

    f32x16 acc[2][2];
#pragma unroll
    for (int mt = 0; mt < 2; ++mt)
#pragma unroll
        for (int nt = 0; nt < 2; ++nt)
#pragma unroll
            for (int j = 0; j < 16; ++j) acc[mt][nt][j] = 0.f;

    // staging: waves 0-1 stage A half (wave&1), waves 2-3 stage B half (wave&1).
    // Lane l fetches global chunk (l&3)^((l>>3)&3) of row (l>>2); 4 instr/iter.
    const bool stB = wave >= 2;
    const int lr = lane >> 2;
    const int cg = (lane & 3) ^ ((lane >> 3) & 3);
    const unsigned char* gsrc =
        hn8 + (size_t)((stB ? colBase : rowBase) + (wave & 1) * 64 + lr) * D_SZ + cg * 16;
    unsigned char* ldst = (stB ? Bs : As) + (wave & 1) * 64 * BKB;

    // LDS read addrs (k-invariant): logical chunk c of row r sits at c^((r>>1)&3).
    const int sz = (l32 >> 1) & 3;
    const int p0 = (2 * half) ^ sz;
    const int p1 = p0 ^ 1;
    const unsigned char* aLo = &As[(wq_m * 64 + l32) * BKB + p0 * 16];
    const unsigned char* aHi = &As[(wq_m * 64 + l32) * BKB + p1 * 16];
    const unsigned char* bLo = &Bs[(wq_n * 64 + l32) * BKB + p0 * 16];
    const unsigned char* bHi = &Bs[(wq_n * 64 + l32) * BKB + p1 * 16];

    for (int k0 = 0; k0 < D_SZ; k0 += BKB) {
        __syncthreads();
#pragma unroll
        for (int t = 0; t < 4; ++t)
            async16(gsrc + k0 + (size_t)t * 16 * D_SZ, ldst + t * 16 * BKB);
        __syncthreads();

        i32x8 a[2], bf[2];
#pragma unroll
        for (int mt = 0; mt < 2; ++mt) {
            i32x4 lo = *(const i32x4*)(aLo + mt * 32 * BKB);
            i32x4 hi = *(const i32x4*)(aHi + mt * 32 * BKB);
            a[mt] = (i32x8){lo[0], lo[1], lo[2], lo[3], hi[0], hi[1], hi[2], hi[3]};
        }
#pragma unroll
        for (int nt = 0; nt < 2; ++nt) {
            i32x4 lo = *(const i32x4*)(bLo + nt * 32 * BKB);
            i32x4 hi = *(const i32x4*)(bHi + nt * 32 * BKB);
            bf[nt] = (i32x8){lo[0], lo[1], lo[2], lo[3], hi[0], hi[1], hi[2], hi[3]};
        }
#pragma unroll
        for (int mt = 0; mt < 2; ++mt)
#pragma unroll
            for (int nt = 0; nt < 2; ++nt)
                acc[mt][nt] = __builtin_amdgcn_mfma_scale_f32_32x32x64_f8f6f4(
                    a[mt], bf[nt], acc[mt][nt], 0, 0, 0, 0x7F7F7F7F, 0, 0x7F7F7F7F);
    }

    // epilogue: 32x32 C/D layout col=l32, row=(j&3)+8*(j>>2)+4*half (verified).
    float rs[2][16];
#pragma unroll
    for (int mt = 0; mt < 2; ++mt)
#pragma unroll
        for (int j = 0; j < 16; ++j) rs[mt][j] = 0.f;
#pragma unroll
    for (int nt = 0; nt < 2; ++nt) {
        const int col = colBase + wq_n * 64 + nt * 32 + l32;
        float cs = 0.f;
#pragma unroll
        for (int mt = 0; mt < 2; ++mt) {
#pragma unroll
            for (int j = 0; j < 16; ++j) {
                int row = rowBase + wq_m * 64 + mt * 32 + (j & 3) + 8 * (j >> 2) + 4 * half;
                float e = __expf(acc[mt][nt][j] * INV_T);
                e = (diagBlk && row == col) ? 0.f : e;
                rs[mt][j] += e;
                cs += e;
            }
        }
        if (!diagBlk) {
            cs += __shfl_xor(cs, 32, 64);  // add other half's rows
            if (half == 0) atomicAdd(&rowsum[col], cs);
        }
    }
#pragma unroll
    for (int mt = 0; mt < 2; ++mt)
#pragma unroll
        for (int j = 0; j < 16; ++j) {
            float s = rs[mt][j];
#pragma unroll
            for (int m = 1; m < 32; m <<= 1) s += __shfl_xor(s, m, 64);
            if (l32 == 0)
                atomicAdd(&rowsum[rowBase + wq_m * 64 + mt * 32 + (j & 3) + 8 * (j >> 2) + 4 * half], s);
        }
}

// ---- 3) loss = mean(log(rowsum) - pos), 1024 threads, float4 loads ----
__global__ __launch_bounds__(1024) void finalize_k(const float* __restrict__ rowsum,
                                                   const float* __restrict__ pos,
                                                   float* __restrict__ out) {
    __shared__ float red[16];
    const int t = threadIdx.x;
    const float4* rs4 = (const float4*)rowsum;
    const float4* ps4 = (const float4*)pos;
    float s = 0.f;
#pragma unroll
    for (int j = 0; j < 2; ++j) {
        float4 r = rs4[t * 2 + j];
        float4 p = ps4[t * 2 + j];
        s += (__logf(r.x) - p.x) + (__logf(r.y) - p.y) +
             (__logf(r.z) - p.z) + (__logf(r.w) - p.w);
    }
#pragma unroll
    for (int m = 1; m < 64; m <<= 1) s += __shfl_xor(s, m, 64);
    if ((t & 63) == 0) red[t >> 6] = s;
    __syncthreads();
    if (t == 0) {
        float tot = 0.f;
#pragma unroll
        for (int w = 0; w < 16; ++w) tot += red[w];
        out[0] = tot * (1.0f / (float)N_SZ);
    }
}

extern "C" void kernel_launch(void* const* d_in, const int* in_sizes, int n_in,
                              void* d_out, int out_size, void* d_ws, size_t ws_size,
                              hipStream_t stream) {
    const float* h1 = (const float*)d_in[0];
    const float* h2 = (const float*)d_in[1];
    float* out = (float*)d_out;

    char* ws = (char*)d_ws;
    unsigned char* hn8 = (unsigned char*)ws;                      // N*D = 6,291,456 B
    float* pos    = (float*)(ws + (size_t)N_SZ * D_SZ);            // 32 KB
    float* rowsum = (float*)(ws + (size_t)N_SZ * D_SZ + 32768);    // 32 KB

    prep_k<<<B_SZ / 4, 256, 0, stream>>>(h1, h2, hn8, pos, rowsum);
    const int nTiles = N_SZ / BN;                    // 64
    const int nBlocks = nTiles * (nTiles + 1) / 2;   // 2080
    gemm_reduce_k<<<nBlocks, 256, 0, stream>>>(hn8, rowsum);
    finalize_k<<<1, 1024, 0, stream>>>(rowsum, pos, out);
}

// Round 9
// 132.503 us; speedup vs baseline: 1.5194x; 1.5194x over previous
//
#include <hip/hip_runtime.h>
#include <hip/hip_bf16.h>

// InfoNCE loss, B=4096 D=768 N=8192, T=0.5, fp32 in, fp32 scalar out.
// R9 = R7 (best: gemm 65.5us; 512 thr, wave=32x64, acc=2xf32x16=32 VGPR)
//      + double-buffered LDS, ONE barrier per k-iter: prefetch for iter i+1
//      issues right after the barrier, so the vmcnt(0) drain at the next
//      barrier is nearly free (R7 issued loads immediately before the drain,
//      exposing full ~300-900 cyc load latency x12 iters).
// R8 lesson: per-wave C-footprint >32x64 -> 236 VGPR, 10% occupancy, 2x slower.
// R5/R6 lesson: never cap regs via launch_bounds (acc spills to scratch).

#define B_SZ 4096
#define D_SZ 768
#define N_SZ 8192
constexpr float INV_T = 2.0f;  // 1/temperature

typedef float f32x16 __attribute__((ext_vector_type(16)));
typedef int i32x8 __attribute__((ext_vector_type(8)));
typedef int i32x4 __attribute__((ext_vector_type(4)));
typedef __attribute__((address_space(1))) const unsigned int gu32;
typedef __attribute__((address_space(3))) unsigned int lu32;

__device__ inline void async16(const void* g, void* l) {
    // per-lane global addr, wave-uniform LDS base; lane i lands at base + i*16.
    __builtin_amdgcn_global_load_lds((gu32*)g, (lu32*)l, 16, 0, 0);
}

// ---- 1) fused prep: norms + positives + e4m3 rows + rowsum zeroing ----
__global__ __launch_bounds__(256) void prep_k(const float* __restrict__ h1,
                                              const float* __restrict__ h2,
                                              unsigned char* __restrict__ hn8,
                                              float* __restrict__ pos,
                                              float* __restrict__ rowsum) {
    const int i = blockIdx.x * 4 + (threadIdx.x >> 6);
    const int lane = threadIdx.x & 63;
    const float4* a4 = (const float4*)(h1 + (size_t)i * D_SZ);
    const float4* b4 = (const float4*)(h2 + (size_t)i * D_SZ);
    float4 av[3], bv[3];
    float sa = 0.f, sb = 0.f, dt = 0.f;
#pragma unroll
    for (int j = 0; j < 3; ++j) {
        av[j] = a4[lane + j * 64];
        bv[j] = b4[lane + j * 64];
        sa += av[j].x * av[j].x + av[j].y * av[j].y + av[j].z * av[j].z + av[j].w * av[j].w;
        sb += bv[j].x * bv[j].x + bv[j].y * bv[j].y + bv[j].z * bv[j].z + bv[j].w * bv[j].w;
        dt += av[j].x * bv[j].x + av[j].y * bv[j].y + av[j].z * bv[j].z + av[j].w * bv[j].w;
    }
#pragma unroll
    for (int m = 1; m < 64; m <<= 1) {
        sa += __shfl_xor(sa, m, 64);
        sb += __shfl_xor(sb, m, 64);
        dt += __shfl_xor(dt, m, 64);
    }
    const float n1 = fmaxf(sqrtf(sa), 1e-8f), n2 = fmaxf(sqrtf(sb), 1e-8f);
    const float i1 = 1.0f / n1, i2 = 1.0f / n2;
    unsigned int* d1 = (unsigned int*)(hn8 + (size_t)i * D_SZ);
    unsigned int* d2 = (unsigned int*)(hn8 + (size_t)(i + B_SZ) * D_SZ);
#pragma unroll
    for (int j = 0; j < 3; ++j) {
        unsigned int u1 = __builtin_amdgcn_cvt_pk_fp8_f32(av[j].x * i1, av[j].y * i1, 0, false);
        u1 = __builtin_amdgcn_cvt_pk_fp8_f32(av[j].z * i1, av[j].w * i1, u1, true);
        unsigned int u2 = __builtin_amdgcn_cvt_pk_fp8_f32(bv[j].x * i2, bv[j].y * i2, 0, false);
        u2 = __builtin_amdgcn_cvt_pk_fp8_f32(bv[j].z * i2, bv[j].w * i2, u2, true);
        d1[lane + j * 64] = u1;
        d2[lane + j * 64] = u2;
    }
    if (lane == 0) {
        float p = dt * i1 * i2 * INV_T;
        pos[i] = p;
        pos[i + B_SZ] = p;
        rowsum[i] = 0.f;  // ws re-poisoned each call; zero here
        rowsum[i + B_SZ] = 0.f;
    }
}

// ---- 2) symmetric fused sim-GEMM (MX-fp8, 32x32x64) + exp-rowsum ----
// 128x128 tile, 8 waves: wave w = m-strip (w&3)*32 x n-half (w>>2)*64.
// Unpadded 64 B LDS rows for global_load_lds w16; chunk-XOR swizzle for banks.
#define BM 128
#define BN 128
#define BKB 64              // fp8 bytes along K per iter
#define BUFSZ (BM * BKB)    // 8192 B per buffer
#define KITERS (D_SZ / BKB) // 12

__global__ __launch_bounds__(512) void gemm_reduce_k(const unsigned char* __restrict__ hn8,
                                                     float* __restrict__ rowsum) {
    __shared__ __align__(16) unsigned char As[2 * BUFSZ];  // 16 KB (double-buffered)
    __shared__ __align__(16) unsigned char Bs[2 * BUFSZ];  // 16 KB
    // triangular index -> (ty, tx), ty <= tx
    const int b = blockIdx.x;
    int tx = (int)((sqrtf(8.0f * (float)b + 1.0f) - 1.0f) * 0.5f);
    while ((tx + 1) * (tx + 2) / 2 <= b) ++tx;
    while (tx * (tx + 1) / 2 > b) --tx;
    const int ty = b - tx * (tx + 1) / 2;
    const int rowBase = ty * BM;
    const int colBase = tx * BN;
    const bool diagBlk = (ty == tx);

    const int tid = threadIdx.x;
    const int wave = tid >> 6;   // 0..7
    const int lane = tid & 63;
    const int l32 = lane & 31;
    const int half = lane >> 5;
    const int ms = wave & 3;     // m-strip (32 rows)
    const int nh = wave >> 2;    // n-half (64 cols)

    f32x16 acc[2];
#pragma unroll
    for (int nt = 0; nt < 2; ++nt)
#pragma unroll
        for (int j = 0; j < 16; ++j) acc[nt][j] = 0.f;

    // staging: waves 0-3 stage A strip ms, waves 4-7 stage B strip ms.
    // Lane l fetches global chunk (l&3)^((l>>3)&3) of row (l>>2); 2 instr/iter.
    const bool stB = wave >= 4;
    const int lr = lane >> 2;
    const int cg = (lane & 3) ^ ((lane >> 3) & 3);
    const unsigned char* gsrc =
        hn8 + (size_t)((stB ? colBase : rowBase) + ms * 32 + lr) * D_SZ + cg * 16;
    unsigned char* ldst = (stB ? Bs : As) + ms * 32 * BKB;  // buffer 0; buffer 1 = +BUFSZ

    // LDS read offsets (k-invariant): logical chunk c of row r sits at c^((r>>1)&3).
    const int sz = (l32 >> 1) & 3;
    const int p0 = (2 * half) ^ sz;
    const int p1 = p0 ^ 1;
    const int aRow = (ms * 32 + l32) * BKB;
    const int bRow0 = (nh * 64 + l32) * BKB;

    // prologue: stage k-slab 0 into buffer 0
    async16(gsrc, ldst);
    async16(gsrc + (size_t)16 * D_SZ, ldst + 16 * BKB);

    for (int i = 0; i < KITERS; ++i) {
        __syncthreads();  // drains prefetch (issued a full compute-phase ago) + prior reads
        const int buf = i & 1;
        if (i + 1 < KITERS) {  // prefetch next slab into the other buffer
            unsigned char* nb = ldst + ((i + 1) & 1) * BUFSZ;
            const unsigned char* ng = gsrc + (i + 1) * BKB;
            async16(ng, nb);
            async16(ng + (size_t)16 * D_SZ, nb + 16 * BKB);
        }
        const unsigned char* Ab = As + buf * BUFSZ;
        const unsigned char* Bb = Bs + buf * BUFSZ;

        i32x4 alo = *(const i32x4*)(Ab + aRow + p0 * 16);
        i32x4 ahi = *(const i32x4*)(Ab + aRow + p1 * 16);
        i32x8 a = {alo[0], alo[1], alo[2], alo[3], ahi[0], ahi[1], ahi[2], ahi[3]};
#pragma unroll
        for (int nt = 0; nt < 2; ++nt) {
            i32x4 blo = *(const i32x4*)(Bb + bRow0 + nt * 32 * BKB + p0 * 16);
            i32x4 bhi = *(const i32x4*)(Bb + bRow0 + nt * 32 * BKB + p1 * 16);
            i32x8 bf = {blo[0], blo[1], blo[2], blo[3], bhi[0], bhi[1], bhi[2], bhi[3]};
            acc[nt] = __builtin_amdgcn_mfma_scale_f32_32x32x64_f8f6f4(
                a, bf, acc[nt], 0, 0, 0, 0x7F7F7F7F, 0, 0x7F7F7F7F);
        }
    }

    // epilogue: 32x32 C/D layout col=l32, row=(j&3)+8*(j>>2)+4*half (verified).
    float rs[16];
#pragma unroll
    for (int j = 0; j < 16; ++j) rs[j] = 0.f;
#pragma unroll
    for (int nt = 0; nt < 2; ++nt) {
        const int col = colBase + nh * 64 + nt * 32 + l32;
        float cs = 0.f;
#pragma unroll
        for (int j = 0; j < 16; ++j) {
            int row = rowBase + ms * 32 + (j & 3) + 8 * (j >> 2) + 4 * half;
            float e = __expf(acc[nt][j] * INV_T);
            e = (diagBlk && row == col) ? 0.f : e;
            rs[j] += e;
            cs += e;
        }
        if (!diagBlk) {
            cs += __shfl_xor(cs, 32, 64);
            if (half == 0) atomicAdd(&rowsum[col], cs);
        }
    }
#pragma unroll
    for (int j = 0; j < 16; ++j) {
        float s = rs[j];
#pragma unroll
        for (int m = 1; m < 32; m <<= 1) s += __shfl_xor(s, m, 64);
        if (l32 == 0)
            atomicAdd(&rowsum[rowBase + ms * 32 + (j & 3) + 8 * (j >> 2) + 4 * half], s);
    }
}

// ---- 3) loss = mean(log(rowsum) - pos), 1024 threads, float4 loads ----
__global__ __launch_bounds__(1024) void finalize_k(const float* __restrict__ rowsum,
                                                   const float* __restrict__ pos,
                                                   float* __restrict__ out) {
    __shared__ float red[16];
    const int t = threadIdx.x;
    const float4* rs4 = (const float4*)rowsum;
    const float4* ps4 = (const float4*)pos;
    float s = 0.f;
#pragma unroll
    for (int j = 0; j < 2; ++j) {
        float4 r = rs4[t * 2 + j];
        float4 p = ps4[t * 2 + j];
        s += (__logf(r.x) - p.x) + (__logf(r.y) - p.y) +
             (__logf(r.z) - p.z) + (__logf(r.w) - p.w);
    }
#pragma unroll
    for (int m = 1; m < 64; m <<= 1) s += __shfl_xor(s, m, 64);
    if ((t & 63) == 0) red[t >> 6] = s;
    __syncthreads();
    if (t == 0) {
        float tot = 0.f;
#pragma unroll
        for (int w = 0; w < 16; ++w) tot += red[w];
        out[0] = tot * (1.0f / (float)N_SZ);
    }
}

extern "C" void kernel_launch(void* const* d_in, const int* in_sizes, int n_in,
                              void* d_out, int out_size, void* d_ws, size_t ws_size,
                              hipStream_t stream) {
    const float* h1 = (const float*)d_in[0];
    const float* h2 = (const float*)d_in[1];
    float* out = (float*)d_out;

    char* ws = (char*)d_ws;
    unsigned char* hn8 = (unsigned char*)ws;                      // N*D = 6,291,456 B
    float* pos    = (float*)(ws + (size_t)N_SZ * D_SZ);            // 32 KB
    float* rowsum = (float*)(ws + (size_t)N_SZ * D_SZ + 32768);    // 32 KB

    prep_k<<<B_SZ / 4, 256, 0, stream>>>(h1, h2, hn8, pos, rowsum);
    const int nTiles = N_SZ / BN;                    // 64
    const int nBlocks = nTiles * (nTiles + 1) / 2;   // 2080
    gemm_reduce_k<<<nBlocks, 512, 0, stream>>>(hn8, rowsum);
    finalize_k<<<1, 1024, 0, stream>>>(rowsum, pos, out);
}

// Round 10
// 126.661 us; speedup vs baseline: 1.5894x; 1.0461x over previous
//
#include <hip/hip_runtime.h>
#include <hip/hip_bf16.h>

// InfoNCE loss, B=4096 D=768 N=8192, T=0.5, fp32 in, fp32 scalar out.
// R10 = R7 structure (512 thr, wave=32x64, acc=2xf32x16) but TWO k-slabs per
// barrier pair: stage 2x8KB buffers with 4 async16/wave in one window, then
// 2 MFMA k-steps -> 12 barrier events/block instead of 24. R9 falsified the
// load-latency theory (dbuf neutral); residual cost attributed to per-barrier
// fixed costs + short-K amortization. Same verified swizzle/epilogue.
// Lessons kept: no launch_bounds reg cap (R5/R6); wave C-tile <= 32x64 (R4/R8).

#define B_SZ 4096
#define D_SZ 768
#define N_SZ 8192
constexpr float INV_T = 2.0f;  // 1/temperature

typedef float f32x16 __attribute__((ext_vector_type(16)));
typedef int i32x8 __attribute__((ext_vector_type(8)));
typedef int i32x4 __attribute__((ext_vector_type(4)));
typedef __attribute__((address_space(1))) const unsigned int gu32;
typedef __attribute__((address_space(3))) unsigned int lu32;

__device__ inline void async16(const void* g, void* l) {
    // per-lane global addr, wave-uniform LDS base; lane i lands at base + i*16.
    __builtin_amdgcn_global_load_lds((gu32*)g, (lu32*)l, 16, 0, 0);
}

// ---- 1) fused prep: norms + positives + e4m3 rows + rowsum zeroing ----
__global__ __launch_bounds__(256) void prep_k(const float* __restrict__ h1,
                                              const float* __restrict__ h2,
                                              unsigned char* __restrict__ hn8,
                                              float* __restrict__ pos,
                                              float* __restrict__ rowsum) {
    const int i = blockIdx.x * 4 + (threadIdx.x >> 6);
    const int lane = threadIdx.x & 63;
    const float4* a4 = (const float4*)(h1 + (size_t)i * D_SZ);
    const float4* b4 = (const float4*)(h2 + (size_t)i * D_SZ);
    float4 av[3], bv[3];
    float sa = 0.f, sb = 0.f, dt = 0.f;
#pragma unroll
    for (int j = 0; j < 3; ++j) {
        av[j] = a4[lane + j * 64];
        bv[j] = b4[lane + j * 64];
        sa += av[j].x * av[j].x + av[j].y * av[j].y + av[j].z * av[j].z + av[j].w * av[j].w;
        sb += bv[j].x * bv[j].x + bv[j].y * bv[j].y + bv[j].z * bv[j].z + bv[j].w * bv[j].w;
        dt += av[j].x * bv[j].x + av[j].y * bv[j].y + av[j].z * bv[j].z + av[j].w * bv[j].w;
    }
#pragma unroll
    for (int m = 1; m < 64; m <<= 1) {
        sa += __shfl_xor(sa, m, 64);
        sb += __shfl_xor(sb, m, 64);
        dt += __shfl_xor(dt, m, 64);
    }
    const float n1 = fmaxf(sqrtf(sa), 1e-8f), n2 = fmaxf(sqrtf(sb), 1e-8f);
    const float i1 = 1.0f / n1, i2 = 1.0f / n2;
    unsigned int* d1 = (unsigned int*)(hn8 + (size_t)i * D_SZ);
    unsigned int* d2 = (unsigned int*)(hn8 + (size_t)(i + B_SZ) * D_SZ);
#pragma unroll
    for (int j = 0; j < 3; ++j) {
        unsigned int u1 = __builtin_amdgcn_cvt_pk_fp8_f32(av[j].x * i1, av[j].y * i1, 0, false);
        u1 = __builtin_amdgcn_cvt_pk_fp8_f32(av[j].z * i1, av[j].w * i1, u1, true);
        unsigned int u2 = __builtin_amdgcn_cvt_pk_fp8_f32(bv[j].x * i2, bv[j].y * i2, 0, false);
        u2 = __builtin_amdgcn_cvt_pk_fp8_f32(bv[j].z * i2, bv[j].w * i2, u2, true);
        d1[lane + j * 64] = u1;
        d2[lane + j * 64] = u2;
    }
    if (lane == 0) {
        float p = dt * i1 * i2 * INV_T;
        pos[i] = p;
        pos[i + B_SZ] = p;
        rowsum[i] = 0.f;  // ws re-poisoned each call; zero here
        rowsum[i + B_SZ] = 0.f;
    }
}

// ---- 2) symmetric fused sim-GEMM (MX-fp8, 32x32x64) + exp-rowsum ----
// 128x128 tile, 8 waves: wave w = m-strip (w&3)*32 x n-half (w>>2)*64.
// Unpadded 64 B LDS rows for global_load_lds w16; chunk-XOR swizzle for banks.
#define BM 128
#define BN 128
#define BKB 64              // fp8 bytes along K per slab
#define BUFSZ (BM * BKB)    // 8192 B per slab buffer
#define OUTER (D_SZ / (2 * BKB))  // 6 iterations, 2 slabs each

__global__ __launch_bounds__(512) void gemm_reduce_k(const unsigned char* __restrict__ hn8,
                                                     float* __restrict__ rowsum) {
    __shared__ __align__(16) unsigned char As[2 * BUFSZ];  // 16 KB (two slabs)
    __shared__ __align__(16) unsigned char Bs[2 * BUFSZ];  // 16 KB
    // triangular index -> (ty, tx), ty <= tx
    const int b = blockIdx.x;
    int tx = (int)((sqrtf(8.0f * (float)b + 1.0f) - 1.0f) * 0.5f);
    while ((tx + 1) * (tx + 2) / 2 <= b) ++tx;
    while (tx * (tx + 1) / 2 > b) --tx;
    const int ty = b - tx * (tx + 1) / 2;
    const int rowBase = ty * BM;
    const int colBase = tx * BN;
    const bool diagBlk = (ty == tx);

    const int tid = threadIdx.x;
    const int wave = tid >> 6;   // 0..7
    const int lane = tid & 63;
    const int l32 = lane & 31;
    const int half = lane >> 5;
    const int ms = wave & 3;     // m-strip (32 rows)
    const int nh = wave >> 2;    // n-half (64 cols)

    f32x16 acc[2];
#pragma unroll
    for (int nt = 0; nt < 2; ++nt)
#pragma unroll
        for (int j = 0; j < 16; ++j) acc[nt][j] = 0.f;

    // staging: waves 0-3 stage A strip ms, waves 4-7 stage B strip ms.
    // Lane l fetches global chunk (l&3)^((l>>3)&3) of row (l>>2); 4 instr per
    // outer iter (2 slabs x 2 row-groups).
    const bool stB = wave >= 4;
    const int lr = lane >> 2;
    const int cg = (lane & 3) ^ ((lane >> 3) & 3);
    const unsigned char* gsrc =
        hn8 + (size_t)((stB ? colBase : rowBase) + ms * 32 + lr) * D_SZ + cg * 16;
    unsigned char* ldst = (stB ? Bs : As) + ms * 32 * BKB;  // slab0; slab1 = +BUFSZ

    // LDS read offsets (k-invariant): logical chunk c of row r sits at c^((r>>1)&3).
    const int sz = (l32 >> 1) & 3;
    const int p0 = (2 * half) ^ sz;
    const int p1 = p0 ^ 1;
    const int aRow = (ms * 32 + l32) * BKB;
    const int bRow0 = (nh * 64 + l32) * BKB;

    for (int i = 0; i < OUTER; ++i) {
        __syncthreads();  // prior iteration's LDS reads complete
        const unsigned char* g0 = gsrc + i * (2 * BKB);
        async16(g0, ldst);                                   // slab 0, rows 0-15
        async16(g0 + (size_t)16 * D_SZ, ldst + 16 * BKB);    // slab 0, rows 16-31
        async16(g0 + BKB, ldst + BUFSZ);                     // slab 1, rows 0-15
        async16(g0 + BKB + (size_t)16 * D_SZ, ldst + BUFSZ + 16 * BKB);
        __syncthreads();  // staging complete

#pragma unroll
        for (int kk = 0; kk < 2; ++kk) {
            const unsigned char* Ab = As + kk * BUFSZ;
            const unsigned char* Bb = Bs + kk * BUFSZ;
            i32x4 alo = *(const i32x4*)(Ab + aRow + p0 * 16);
            i32x4 ahi = *(const i32x4*)(Ab + aRow + p1 * 16);
            i32x8 a = {alo[0], alo[1], alo[2], alo[3], ahi[0], ahi[1], ahi[2], ahi[3]};
#pragma unroll
            for (int nt = 0; nt < 2; ++nt) {
                i32x4 blo = *(const i32x4*)(Bb + bRow0 + nt * 32 * BKB + p0 * 16);
                i32x4 bhi = *(const i32x4*)(Bb + bRow0 + nt * 32 * BKB + p1 * 16);
                i32x8 bf = {blo[0], blo[1], blo[2], blo[3], bhi[0], bhi[1], bhi[2], bhi[3]};
                acc[nt] = __builtin_amdgcn_mfma_scale_f32_32x32x64_f8f6f4(
                    a, bf, acc[nt], 0, 0, 0, 0x7F7F7F7F, 0, 0x7F7F7F7F);
            }
        }
    }

    // epilogue: 32x32 C/D layout col=l32, row=(j&3)+8*(j>>2)+4*half (verified).
    float rs[16];
#pragma unroll
    for (int j = 0; j < 16; ++j) rs[j] = 0.f;
#pragma unroll
    for (int nt = 0; nt < 2; ++nt) {
        const int col = colBase + nh * 64 + nt * 32 + l32;
        float cs = 0.f;
#pragma unroll
        for (int j = 0; j < 16; ++j) {
            int row = rowBase + ms * 32 + (j & 3) + 8 * (j >> 2) + 4 * half;
            float e = __expf(acc[nt][j] * INV_T);
            e = (diagBlk && row == col) ? 0.f : e;
            rs[j] += e;
            cs += e;
        }
        if (!diagBlk) {
            cs += __shfl_xor(cs, 32, 64);
            if (half == 0) atomicAdd(&rowsum[col], cs);
        }
    }
#pragma unroll
    for (int j = 0; j < 16; ++j) {
        float s = rs[j];
#pragma unroll
        for (int m = 1; m < 32; m <<= 1) s += __shfl_xor(s, m, 64);
        if (l32 == 0)
            atomicAdd(&rowsum[rowBase + ms * 32 + (j & 3) + 8 * (j >> 2) + 4 * half], s);
    }
}

// ---- 3) loss = mean(log(rowsum) - pos), 1024 threads, float4 loads ----
__global__ __launch_bounds__(1024) void finalize_k(const float* __restrict__ rowsum,
                                                   const float* __restrict__ pos,
                                                   float* __restrict__ out) {
    __shared__ float red[16];
    const int t = threadIdx.x;
    const float4* rs4 = (const float4*)rowsum;
    const float4* ps4 = (const float4*)pos;
    float s = 0.f;
#pragma unroll
    for (int j = 0; j < 2; ++j) {
        float4 r = rs4[t * 2 + j];
        float4 p = ps4[t * 2 + j];
        s += (__logf(r.x) - p.x) + (__logf(r.y) - p.y) +
             (__logf(r.z) - p.z) + (__logf(r.w) - p.w);
    }
#pragma unroll
    for (int m = 1; m < 64; m <<= 1) s += __shfl_xor(s, m, 64);
    if ((t & 63) == 0) red[t >> 6] = s;
    __syncthreads();
    if (t == 0) {
        float tot = 0.f;
#pragma unroll
        for (int w = 0; w < 16; ++w) tot += red[w];
        out[0] = tot * (1.0f / (float)N_SZ);
    }
}

extern "C" void kernel_launch(void* const* d_in, const int* in_sizes, int n_in,
                              void* d_out, int out_size, void* d_ws, size_t ws_size,
                              hipStream_t stream) {
    const float* h1 = (const float*)d_in[0];
    const float* h2 = (const float*)d_in[1];
    float* out = (float*)d_out;

    char* ws = (char*)d_ws;
    unsigned char* hn8 = (unsigned char*)ws;                      // N*D = 6,291,456 B
    float* pos    = (float*)(ws + (size_t)N_SZ * D_SZ);            // 32 KB
    float* rowsum = (float*)(ws + (size_t)N_SZ * D_SZ + 32768);    // 32 KB

    prep_k<<<B_SZ / 4, 256, 0, stream>>>(h1, h2, hn8, pos, rowsum);
    const int nTiles = N_SZ / BN;                    // 64
    const int nBlocks = nTiles * (nTiles + 1) / 2;   // 2080
    gemm_reduce_k<<<nBlocks, 512, 0, stream>>>(hn8, rowsum);
    finalize_k<<<1, 1024, 0, stream>>>(rowsum, pos, out);
}

// Round 11
// 118.245 us; speedup vs baseline: 1.7026x; 1.0712x over previous
//
#include <hip/hip_runtime.h>
#include <hip/hip_bf16.h>

// InfoNCE loss, B=4096 D=768 N=8192, T=0.5, fp32 in, fp32 scalar out.
// R11: MX-fp4 GEMM. Rows encoded e2m1 x16 with e8m0 scale 2^-4 on both
// operands (software encoder in prep; A/B pack identically so any
// within-lane k-permutation cancels in the dot product). All gemm costs
// scale with operand bytes: frag = one ds_read_b128 (was 2), staged bytes
// halve, fp4 MFMA rate 2x fp8 (m59: 9099 TF). Window K=256 -> 6 barrier
// events (R10 showed ~0.5us/event). Wave C-tile 32x64 (R4/R8 lesson),
// no launch_bounds reg cap (R5/R6 lesson).

#define B_SZ 4096
#define D_SZ 768
#define N_SZ 8192
#define ROWB 384  // fp4 bytes per row (768 * 0.5)
constexpr float INV_T = 2.0f;  // 1/temperature

typedef float f32x16 __attribute__((ext_vector_type(16)));
typedef int i32x8 __attribute__((ext_vector_type(8)));
typedef int i32x4 __attribute__((ext_vector_type(4)));
typedef __attribute__((address_space(1))) const unsigned int gu32;
typedef __attribute__((address_space(3))) unsigned int lu32;

__device__ inline void async16(const void* g, void* l) {
    // per-lane global addr, wave-uniform LDS base; lane i lands at base + i*16.
    __builtin_amdgcn_global_load_lds((gu32*)g, (lu32*)l, 16, 0, 0);
}

// e2m1 encode of v (pre-scaled); levels 0,.5,1,1.5,2,3,4,6; round-to-nearest.
__device__ inline unsigned fp4_enc(float v) {
    float a = fabsf(v);
    unsigned c;
    if (a < 1.25f)      c = (a < 0.25f) ? 0u : (a < 0.75f) ? 1u : 2u;
    else if (a < 2.5f)  c = (a < 1.75f) ? 3u : 4u;
    else                c = (a < 3.5f) ? 5u : (a < 5.0f) ? 6u : 7u;
    return c | (v < 0.f ? 8u : 0u);
}

// ---- 1) fused prep: norms + positives + fp4 rows + rowsum zeroing ----
// One wave per pair i. Lane l owns elements 12l..12l+11 (3 contiguous float4).
__global__ __launch_bounds__(256) void prep_k(const float* __restrict__ h1,
                                              const float* __restrict__ h2,
                                              unsigned char* __restrict__ hn4,
                                              float* __restrict__ pos,
                                              float* __restrict__ rowsum) {
    const int i = blockIdx.x * 4 + (threadIdx.x >> 6);
    const int lane = threadIdx.x & 63;
    const float4* a4 = (const float4*)(h1 + (size_t)i * D_SZ);
    const float4* b4 = (const float4*)(h2 + (size_t)i * D_SZ);
    float4 av[3], bv[3];
    float sa = 0.f, sb = 0.f, dt = 0.f;
#pragma unroll
    for (int j = 0; j < 3; ++j) {
        av[j] = a4[lane * 3 + j];
        bv[j] = b4[lane * 3 + j];
        sa += av[j].x * av[j].x + av[j].y * av[j].y + av[j].z * av[j].z + av[j].w * av[j].w;
        sb += bv[j].x * bv[j].x + bv[j].y * bv[j].y + bv[j].z * bv[j].z + bv[j].w * bv[j].w;
        dt += av[j].x * bv[j].x + av[j].y * bv[j].y + av[j].z * bv[j].z + av[j].w * bv[j].w;
    }
#pragma unroll
    for (int m = 1; m < 64; m <<= 1) {
        sa += __shfl_xor(sa, m, 64);
        sb += __shfl_xor(sb, m, 64);
        dt += __shfl_xor(dt, m, 64);
    }
    const float n1 = fmaxf(sqrtf(sa), 1e-8f), n2 = fmaxf(sqrtf(sb), 1e-8f);
    const float i1 = 1.0f / n1, i2 = 1.0f / n2;
    const float s1 = i1 * 16.0f, s2 = i2 * 16.0f;  // fp4 stores v*16, scale 2^-4
    unsigned short* d1 = (unsigned short*)(hn4 + (size_t)i * ROWB);
    unsigned short* d2 = (unsigned short*)(hn4 + (size_t)(i + B_SZ) * ROWB);
#pragma unroll
    for (int j = 0; j < 3; ++j) {
        float va[4] = {av[j].x, av[j].y, av[j].z, av[j].w};
        float vb[4] = {bv[j].x, bv[j].y, bv[j].z, bv[j].w};
        unsigned u1 = 0, u2 = 0;
#pragma unroll
        for (int e = 0; e < 4; ++e) {
            u1 |= fp4_enc(va[e] * s1) << (4 * e);
            u2 |= fp4_enc(vb[e] * s2) << (4 * e);
        }
        d1[lane * 3 + j] = (unsigned short)u1;
        d2[lane * 3 + j] = (unsigned short)u2;
    }
    if (lane == 0) {
        float p = dt * i1 * i2 * INV_T;
        pos[i] = p;
        pos[i + B_SZ] = p;
        rowsum[i] = 0.f;  // ws re-poisoned each call; zero here
        rowsum[i + B_SZ] = 0.f;
    }
}

// ---- 2) symmetric fused sim-GEMM (MX-fp4, 32x32x64) + exp-rowsum ----
// 128x128 tile, 8 waves: wave w = m-strip (w&3)*32 x n-half (w>>2)*64.
// LDS: 4 slabs/window per matrix, slab = 128 rows x 32 B (K=64 fp4).
// Swizzle: chunk c of row r at position c^((r>>2)&1) -> conflict-free b128.
#define BM 128
#define BN 128
#define SLAB 4096            // 128 rows * 32 B
#define WINB 128             // fp4 bytes per row per window (K=256)
#define NWIN 3               // 768 / 256

__global__ __launch_bounds__(512) void gemm_reduce_k(const unsigned char* __restrict__ hn4,
                                                     float* __restrict__ rowsum) {
    __shared__ __align__(16) unsigned char As[4 * SLAB];  // 16 KB
    __shared__ __align__(16) unsigned char Bs[4 * SLAB];  // 16 KB
    // triangular index -> (ty, tx), ty <= tx
    const int b = blockIdx.x;
    int tx = (int)((sqrtf(8.0f * (float)b + 1.0f) - 1.0f) * 0.5f);
    while ((tx + 1) * (tx + 2) / 2 <= b) ++tx;
    while (tx * (tx + 1) / 2 > b) --tx;
    const int ty = b - tx * (tx + 1) / 2;
    const int rowBase = ty * BM;
    const int colBase = tx * BN;
    const bool diagBlk = (ty == tx);

    const int tid = threadIdx.x;
    const int wave = tid >> 6;   // 0..7
    const int lane = tid & 63;
    const int l32 = lane & 31;
    const int half = lane >> 5;
    const int ms = wave & 3;     // m-strip (32 rows)
    const int nh = wave >> 2;    // n-half (64 cols)

    f32x16 acc[2];
#pragma unroll
    for (int nt = 0; nt < 2; ++nt)
#pragma unroll
        for (int j = 0; j < 16; ++j) acc[nt][j] = 0.f;

    // staging: waves 0-3 stage A strip ms, waves 4-7 stage B strip ms.
    // Lane l -> row ms*32 + (l>>1); fetches global 16B chunk (l&1)^((l>>3)&1)
    // of the 32-B slab so that after the fixed lane->slot DMA mapping, logical
    // chunk c of row r sits at position c^((r>>2)&1).
    const bool stB = wave >= 4;
    const int cg = (lane & 1) ^ ((lane >> 3) & 1);
    const unsigned char* gsrc =
        hn4 + (size_t)((stB ? colBase : rowBase) + ms * 32 + (lane >> 1)) * ROWB + cg * 16;
    unsigned char* ldst = (stB ? Bs : As) + ms * 1024;  // + s*SLAB per slab

    // frag read offsets (k-invariant): position p = half ^ ((l32>>2)&1).
    const int p = half ^ ((l32 >> 2) & 1);
    const int aOff = (ms * 32 + l32) * 32 + p * 16;
    const int bOff = (nh * 64 + l32) * 32 + p * 16;

    for (int w = 0; w < NWIN; ++w) {
        __syncthreads();  // prior window's LDS reads complete
        const unsigned char* g0 = gsrc + w * WINB;
#pragma unroll
        for (int s = 0; s < 4; ++s)
            async16(g0 + s * 32, ldst + s * SLAB);
        __syncthreads();  // staging complete

#pragma unroll
        for (int s = 0; s < 4; ++s) {
            const unsigned char* Ab = As + s * SLAB;
            const unsigned char* Bb = Bs + s * SLAB;
            i32x4 al = *(const i32x4*)(Ab + aOff);
            i32x8 a = {al[0], al[1], al[2], al[3], 0, 0, 0, 0};
#pragma unroll
            for (int nt = 0; nt < 2; ++nt) {
                i32x4 bl = *(const i32x4*)(Bb + bOff + nt * 1024);
                i32x8 bf = {bl[0], bl[1], bl[2], bl[3], 0, 0, 0, 0};
                // fmtA=fmtB=4 (fp4); e8m0 scale bytes 0x7B = 2^-4 on A and B.
                acc[nt] = __builtin_amdgcn_mfma_scale_f32_32x32x64_f8f6f4(
                    a, bf, acc[nt], 4, 4, 0, 0x7B7B7B7B, 0, 0x7B7B7B7B);
            }
        }
    }

    // epilogue: 32x32 C/D layout col=l32, row=(j&3)+8*(j>>2)+4*half
    // (shape-determined, FMT-independent — verified R5..R10).
    float rs[16];
#pragma unroll
    for (int j = 0; j < 16; ++j) rs[j] = 0.f;
#pragma unroll
    for (int nt = 0; nt < 2; ++nt) {
        const int col = colBase + nh * 64 + nt * 32 + l32;
        float cs = 0.f;
#pragma unroll
        for (int j = 0; j < 16; ++j) {
            int row = rowBase + ms * 32 + (j & 3) + 8 * (j >> 2) + 4 * half;
            float e = __expf(acc[nt][j] * INV_T);
            e = (diagBlk && row == col) ? 0.f : e;
            rs[j] += e;
            cs += e;
        }
        if (!diagBlk) {
            cs += __shfl_xor(cs, 32, 64);
            if (half == 0) atomicAdd(&rowsum[col], cs);
        }
    }
#pragma unroll
    for (int j = 0; j < 16; ++j) {
        float s = rs[j];
#pragma unroll
        for (int m = 1; m < 32; m <<= 1) s += __shfl_xor(s, m, 64);
        if (l32 == 0)
            atomicAdd(&rowsum[rowBase + ms * 32 + (j & 3) + 8 * (j >> 2) + 4 * half], s);
    }
}

// ---- 3) loss = mean(log(rowsum) - pos), 1024 threads, float4 loads ----
__global__ __launch_bounds__(1024) void finalize_k(const float* __restrict__ rowsum,
                                                   const float* __restrict__ pos,
                                                   float* __restrict__ out) {
    __shared__ float red[16];
    const int t = threadIdx.x;
    const float4* rs4 = (const float4*)rowsum;
    const float4* ps4 = (const float4*)pos;
    float s = 0.f;
#pragma unroll
    for (int j = 0; j < 2; ++j) {
        float4 r = rs4[t * 2 + j];
        float4 p = ps4[t * 2 + j];
        s += (__logf(r.x) - p.x) + (__logf(r.y) - p.y) +
             (__logf(r.z) - p.z) + (__logf(r.w) - p.w);
    }
#pragma unroll
    for (int m = 1; m < 64; m <<= 1) s += __shfl_xor(s, m, 64);
    if ((t & 63) == 0) red[t >> 6] = s;
    __syncthreads();
    if (t == 0) {
        float tot = 0.f;
#pragma unroll
        for (int w = 0; w < 16; ++w) tot += red[w];
        out[0] = tot * (1.0f / (float)N_SZ);
    }
}

extern "C" void kernel_launch(void* const* d_in, const int* in_sizes, int n_in,
                              void* d_out, int out_size, void* d_ws, size_t ws_size,
                              hipStream_t stream) {
    const float* h1 = (const float*)d_in[0];
    const float* h2 = (const float*)d_in[1];
    float* out = (float*)d_out;

    char* ws = (char*)d_ws;
    unsigned char* hn4 = (unsigned char*)ws;                       // N*384 = 3,145,728 B
    float* pos    = (float*)(ws + (size_t)N_SZ * ROWB);             // 32 KB
    float* rowsum = (float*)(ws + (size_t)N_SZ * ROWB + 32768);     // 32 KB

    prep_k<<<B_SZ / 4, 256, 0, stream>>>(h1, h2, hn4, pos, rowsum);
    const int nTiles = N_SZ / BN;                    // 64
    const int nBlocks = nTiles * (nTiles + 1) / 2;   // 2080
    gemm_reduce_k<<<nBlocks, 512, 0, stream>>>(hn4, rowsum);
    finalize_k<<<1, 1024, 0, stream>>>(rowsum, pos, out);
}